// Round 10
// baseline (225.817 us; speedup 1.0000x reference)
//
#include <hip/hip_runtime.h>
#include <hip/hip_bf16.h>

#define B_ 256
#define L_ 225
#define D_ 1280
#define H_ 256
#define U_ 256
#define LT 45     // real rows per block-tile (5 * 45 = 225 exact)
#define LTP 48    // padded rows computed (3 MFMA row-frags)

typedef __bf16  bf16x8 __attribute__((ext_vector_type(8)));
typedef float   f32x4  __attribute__((ext_vector_type(4)));
typedef unsigned short u16x8 __attribute__((ext_vector_type(8)));
typedef unsigned short u16x4 __attribute__((ext_vector_type(4)));

__device__ __forceinline__ unsigned short f2bf(float f) {
    union { __hip_bfloat16 h; unsigned short u; } cv;
    cv.h = __float2bfloat16(f);   // RNE
    return cv.u;
}

__device__ __forceinline__ f32x4 bf4_to_f32(u16x4 w) {
    union { unsigned u; float f; } a0, a1, a2, a3;
    a0.u = (unsigned)w[0] << 16; a1.u = (unsigned)w[1] << 16;
    a2.u = (unsigned)w[2] << 16; a3.u = (unsigned)w[3] << 16;
    return (f32x4){a0.f, a1.f, a2.f, a3.f};
}

__device__ __forceinline__ void gload_lds16(const void* g, void* l) {
    __builtin_amdgcn_global_load_lds(
        (const __attribute__((address_space(1))) unsigned int*)g,
        (__attribute__((address_space(3))) unsigned int*)l,
        16, 0, 0);
}

__device__ __forceinline__ float wredsum(float x) {
#pragma unroll
    for (int off = 32; off > 0; off >>= 1) x += __shfl_xor(x, off, 64);
    return x;
}

// ------ kernel 1: merged prep: W1t bf16 transpose + ph = hidden.W2+b1+b2 ----
__global__ void k_prep(const float* __restrict__ W1,
                       const float* __restrict__ hidden,
                       const float* __restrict__ W2,
                       const float* __restrict__ b1,
                       const float* __restrict__ b2,
                       __hip_bfloat16* __restrict__ w1t,
                       float* __restrict__ ph) {
    int bid = blockIdx.x;
    if (bid < 1280) {
        int idx = bid * 256 + threadIdx.x;   // idx = k*U_+u
        int k = idx / U_;
        int u = idx % U_;
        w1t[(size_t)u * D_ + k] = __float2bfloat16(W1[idx]);
    } else {
        __shared__ float sh[H_];
        int b = bid - 1280;
        int u = threadIdx.x;
        sh[u] = hidden[b * H_ + u];
        __syncthreads();
        float acc = b1[u] + b2[u];
#pragma unroll 8
        for (int h = 0; h < H_; ++h) acc += sh[h] * W2[h * U_ + u];
        ph[b * U_ + u] = acc;
    }
}

// ---------------- kernel 2: one-read fused kernel ---------------------------
// 1280 blocks (b = blk/5, tile s5 = blk%5) x 512 threads, 2 blocks/CU.
// K-loop: A f32->bf16 reg-cvt (quads KEPT in 60 VGPRs) + LDS dbuf; B dbuf via
// global_load_lds. Epilogue tanh*V -> exp weights. Context computed from the
// register-held A quads (zero global re-read), reduced via LDS [8][1280].
// LDS: A0@0(6144) A1@6144 | B0@12288(32768) B1@45056 | sL@77824(1536)
//      sW@79360(192) -> 79552 B total (2 blocks/CU).
__global__ __launch_bounds__(512, 4) void k_fused(
        const float* __restrict__ feat,
        const __hip_bfloat16* __restrict__ w1t,
        const float* __restrict__ ph,
        const float* __restrict__ Vv,
        float* __restrict__ num,
        float* __restrict__ den) {
    __shared__ __align__(128) char smem[79552];
    float* sL = (float*)(smem + 77824);
    float* sW = (float*)(smem + 79360);

    const int tid  = threadIdx.x;
    const int lane = tid & 63;
    const int wave = tid >> 6;     // 0..7
    const int blk  = blockIdx.x;
    const int b    = blk / 5;
    const int s5   = blk - b * 5;

    const float* featB = feat + ((size_t)b * L_ + s5 * LT) * D_;

    const int g    = tid >> 5;     // 0..15 -> rows {3g,3g+1,3g+2}
    const int qw   = tid & 31;     // quad-col within each 128-col window
    const int half = qw >> 4;      // participates in steps with (s&1)==half
    const int ql   = qw & 15;      // quad-col within a 64-col K-step

    const float* aRow[3];
    int aOff[3];
#pragma unroll
    for (int i = 0; i < 3; ++i) {
        int r  = 3 * g + i;
        int rc = r < LT ? r : (LT - 1);
        aRow[i] = featB + (size_t)rc * D_ + ql * 4;
        aOff[i] = r * 128 + ((ql * 8) ^ ((r & 7) << 4));
    }

    const __hip_bfloat16* bSrc[4];
#pragma unroll
    for (int p = 0; p < 4; ++p) {
        int sI = p * 512 + tid;
        int u  = sI >> 3;
        int c8 = (sI & 7) ^ (u & 7);
        bSrc[p] = w1t + (size_t)u * D_ + c8 * 8;
    }

    u16x4 hold[10][3];             // 60 VGPRs: the block's A-tile, kept
    f32x4 acc[3][2];
#pragma unroll
    for (int mi = 0; mi < 3; ++mi)
#pragma unroll
        for (int ni = 0; ni < 2; ++ni)
            acc[mi][ni] = (f32x4){0.f, 0.f, 0.f, 0.f};

    const int u0 = wave * 32 + (lane & 15);

    auto stageB = [&](int s) {
        char* bufB = smem + 12288 + (s & 1) * 32768;
#pragma unroll
        for (int p = 0; p < 4; ++p)
            gload_lds16(bSrc[p] + s * 64, bufB + (p * 512 + tid) * 16);
    };
    auto stageA = [&](int s) {     // load f32 -> cvt -> hold + ds_write
        if ((s & 1) == half) {
            char* bufA = smem + (s & 1) * 6144;
#pragma unroll
            for (int i = 0; i < 3; ++i) {
                f32x4 v = *reinterpret_cast<const f32x4*>(aRow[i] + s * 64);
                u16x4 q;
                q[0] = f2bf(v[0]); q[1] = f2bf(v[1]);
                q[2] = f2bf(v[2]); q[3] = f2bf(v[3]);
                hold[s >> 1][i] = q;
                *reinterpret_cast<u16x4*>(bufA + aOff[i]) = q;
            }
        }
    };
    auto compute = [&](int s) {
        const char* bufA = smem + (s & 1) * 6144;
        const char* bufB = smem + 12288 + (s & 1) * 32768;
#pragma unroll
        for (int ks = 0; ks < 2; ++ks) {
            const int kk2 = (ks * 32 + ((lane >> 4) << 3)) * 2;
            bf16x8 a[3], bb[2];
#pragma unroll
            for (int mi = 0; mi < 3; ++mi) {
                int r = mi * 16 + (lane & 15);
                a[mi] = *reinterpret_cast<const bf16x8*>(
                    bufA + r * 128 + (kk2 ^ ((r & 7) << 4)));
            }
            bb[0] = *reinterpret_cast<const bf16x8*>(
                bufB + u0 * 128 + (kk2 ^ ((u0 & 7) << 4)));
            bb[1] = *reinterpret_cast<const bf16x8*>(
                bufB + (u0 + 16) * 128 + (kk2 ^ (((u0 + 16) & 7) << 4)));
#pragma unroll
            for (int mi = 0; mi < 3; ++mi)
#pragma unroll
                for (int ni = 0; ni < 2; ++ni)
                    acc[mi][ni] = __builtin_amdgcn_mfma_f32_16x16x32_bf16(
                        a[mi], bb[ni], acc[mi][ni], 0, 0, 0);
        }
    };

    // ---- K-loop: 20 steps of 64, fully unrolled (static hold indices) ----
    stageB(0);
    stageA(0);
    __syncthreads();
#pragma unroll
    for (int s = 0; s < 20; ++s) {
        if (s < 19) { stageB(s + 1); stageA(s + 1); }
        compute(s);
        __syncthreads();
    }

    // ---- epilogue: tanh(acc+ph)*V -> per-wave partial logits ----
    const float* phB = ph + b * 256;
    float ph0 = phB[u0], ph1 = phB[u0 + 16];
    float v0  = Vv[u0],  v1  = Vv[u0 + 16];
#pragma unroll
    for (int mi = 0; mi < 3; ++mi) {
#pragma unroll
        for (int rg = 0; rg < 4; ++rg) {
            int row = mi * 16 + ((lane >> 4) << 2) + rg;   // 0..47
            float x0 = acc[mi][0][rg] + ph0;
            float x1 = acc[mi][1][rg] + ph1;
            float sl = (1.f - 2.f / (__expf(2.f * x0) + 1.f)) * v0
                     + (1.f - 2.f / (__expf(2.f * x1) + 1.f)) * v1;
            sl += __shfl_xor(sl, 1, 64);
            sl += __shfl_xor(sl, 2, 64);
            sl += __shfl_xor(sl, 4, 64);
            sl += __shfl_xor(sl, 8, 64);
            if ((lane & 15) == 0) sL[wave * LTP + row] = sl;
        }
    }
    __syncthreads();

    // ---- weights w = exp(logit) (no max: |logit| <= sum|V| ~ 13) ----
    if (wave == 0) {
        float w = 0.f;
        if (lane < LT) {
            float lg = 0.f;
#pragma unroll
            for (int wc = 0; wc < 8; ++wc) lg += sL[wc * LTP + lane];
            w = __expf(lg);
            sW[lane] = w;
        }
        if (lane >= LT && lane < LTP) sW[lane] = 0.f;   // pad rows
        float d = wredsum(w);
        if (lane == 0) den[blk] = d;
    }
    __syncthreads();   // sW ready; all GEMM LDS reads done -> pc may overwrite

    // ---- context from register-held A quads: zero global reads ----
    float* pc = (float*)smem;   // [8][1280] f32 = 40960 B
    const float w0 = sW[3 * g], w1 = sW[3 * g + 1], w2 = sW[3 * g + 2];
    if (g < 8) {
#pragma unroll
        for (int w = 0; w < 10; ++w) {
            f32x4 p = w0 * bf4_to_f32(hold[w][0])
                    + w1 * bf4_to_f32(hold[w][1])
                    + w2 * bf4_to_f32(hold[w][2]);
            *reinterpret_cast<f32x4*>(pc + g * 1280 + w * 128 + qw * 4) = p;
        }
    }
    __syncthreads();
    if (g >= 8) {
#pragma unroll
        for (int w = 0; w < 10; ++w) {
            f32x4 p = w0 * bf4_to_f32(hold[w][0])
                    + w1 * bf4_to_f32(hold[w][1])
                    + w2 * bf4_to_f32(hold[w][2]);
            f32x4* dst = reinterpret_cast<f32x4*>(pc + (g - 8) * 1280 + w * 128 + qw * 4);
            *dst += p;
        }
    }
    __syncthreads();
    if (tid < 320) {
        f32x4 s = (f32x4){0.f, 0.f, 0.f, 0.f};
#pragma unroll
        for (int j = 0; j < 8; ++j)
            s += *reinterpret_cast<const f32x4*>(pc + j * 1280 + (tid << 2));
        *reinterpret_cast<f32x4*>(num + (size_t)blk * 1280 + (tid << 2)) = s;
    }
}

// ---------------- kernel 3: combine 5 tile-partials per batch ----------------
__global__ void k_combine(const float* __restrict__ num, const float* __restrict__ den,
                          float* __restrict__ out) {
    int b = blockIdx.x;
    int t = threadIdx.x;   // 0..319
    f32x4 n = (f32x4){0.f, 0.f, 0.f, 0.f};
    float d = 0.f;
#pragma unroll
    for (int s = 0; s < 5; ++s) {
        n += *reinterpret_cast<const f32x4*>(num + (size_t)(b * 5 + s) * 1280 + (t << 2));
        d += den[b * 5 + s];
    }
    n *= (1.f / d);
    *reinterpret_cast<f32x4*>(out + (size_t)b * D_ + (t << 2)) = n;
}

extern "C" void kernel_launch(void* const* d_in, const int* in_sizes, int n_in,
                              void* d_out, int out_size, void* d_ws, size_t ws_size,
                              hipStream_t stream) {
    const float* feat   = (const float*)d_in[0];
    const float* hidden = (const float*)d_in[1];
    const float* W1     = (const float*)d_in[2];
    const float* b1     = (const float*)d_in[3];
    const float* W2     = (const float*)d_in[4];
    const float* b2     = (const float*)d_in[5];
    const float* Vv     = (const float*)d_in[6];
    // bV (d_in[7]) is a uniform logit shift -> softmax-invariant; skipped.

    char* ws = (char*)d_ws;
    __hip_bfloat16* w1t = (__hip_bfloat16*)(ws);    // 655360 B
    float* ph  = (float*)(ws + 655360);             // 262144 B
    float* num = (float*)(ws + 917504);             // 1280*1280*4 = 6553600 B
    float* den = (float*)(ws + 7471104);            // 5120 B
    float* out = (float*)d_out;

    k_prep   <<<1536, 256, 0, stream>>>(W1, hidden, W2, b1, b2, w1t, ph);
    k_fused  <<<B_ * 5, 512, 0, stream>>>(feat, w1t, ph, Vv, num, den);
    k_combine<<<B_, 320, 0, stream>>>(num, den, out);
}